// Round 19
// baseline (792.859 us; speedup 1.0000x reference)
//
#include <hip/hip_runtime.h>
#include <hip/hip_bf16.h>
#include <cmath>

// ATTNLayer fused pipeline, S=E=4096.
// Round 19: r18 + read-rebalance in gemm256 — afr0/b0r reads moved from ph0
// to previous tile's ph3 tail (next-buffer lookahead), published by a new
// vmcnt(4) before ph2's barrier. Sync skeleton otherwise identical to r13.
// [r18: 792.2us, GEMM 119.7/129.6, MfmaUtil 46%]

typedef _Float16 f16;
typedef _Float16 f16x4 __attribute__((ext_vector_type(4)));
typedef _Float16 f16x8 __attribute__((ext_vector_type(8)));
typedef float f32x4 __attribute__((ext_vector_type(4)));

#define S_DIM 4096
#define E_DIM 4096

__device__ __forceinline__ void gload_lds16(const void* g, void* l) {
  __builtin_amdgcn_global_load_lds((const __attribute__((address_space(1))) void*)g,
                                   (__attribute__((address_space(3))) void*)l,
                                   16, 0, 0);
}

// ---------------------------------------------------------------- RMSNorm ---
__global__ __launch_bounds__(256) void rmsnorm_f16(const float* __restrict__ x,
                                                   f16* __restrict__ xq, int E) {
  const int row = blockIdx.x;
  const int t = threadIdx.x;
  const float4* xr = (const float4*)(x + (size_t)row * E);
  float4 v[4];
  float ss = 0.f;
#pragma unroll
  for (int i = 0; i < 4; ++i) {
    v[i] = xr[t + 256 * i];
    ss += v[i].x * v[i].x + v[i].y * v[i].y + v[i].z * v[i].z + v[i].w * v[i].w;
  }
#pragma unroll
  for (int o = 1; o < 64; o <<= 1) ss += __shfl_xor(ss, o);
  __shared__ float red[4];
  const int wid = t >> 6, lane = t & 63;
  if (lane == 0) red[wid] = ss;
  __syncthreads();
  const float tot = red[0] + red[1] + red[2] + red[3];
  const float r = 1.0f / sqrtf(tot / (float)E + 1e-6f);
  f16* xo = xq + (size_t)row * E;
#pragma unroll
  for (int i = 0; i < 4; ++i) {
    f16x4 o;
    o[0] = (f16)(v[i].x * r);
    o[1] = (f16)(v[i].y * r);
    o[2] = (f16)(v[i].z * r);
    o[3] = (f16)(v[i].w * r);
    *(f16x4*)(xo + 4 * (t + 256 * i)) = o;
  }
}

// ------------------------------------------- weight convert + transpose -----
__global__ __launch_bounds__(256) void wconv_t(const float* __restrict__ W,
                                               const float* __restrict__ s,
                                               f16* __restrict__ WT, int N) {
  __shared__ f16 tile[64][65];
  const int tr = blockIdx.y * 64;  // e base
  const int tc = blockIdx.x * 64;  // n base
  const int t = threadIdx.x;
  const int r = t / 16;
  const int c4 = (t % 16) * 4;
#pragma unroll
  for (int i = 0; i < 4; ++i) {
    const int row = r + i * 16;
    float4 w = *(const float4*)(W + (size_t)(tr + row) * N + tc + c4);
    const float sc = s ? s[tr + row] : 1.0f;
    tile[row][c4 + 0] = (f16)(w.x * sc);
    tile[row][c4 + 1] = (f16)(w.y * sc);
    tile[row][c4 + 2] = (f16)(w.z * sc);
    tile[row][c4 + 3] = (f16)(w.w * sc);
  }
  __syncthreads();
#pragma unroll
  for (int i = 0; i < 4; ++i) {
    const int row = r + i * 16;
    f16x4 o;
    o[0] = tile[c4 + 0][row];
    o[1] = tile[c4 + 1][row];
    o[2] = tile[c4 + 2][row];
    o[3] = tile[c4 + 3][row];
    *(f16x4*)(WT + (size_t)(tc + row) * N + tr + c4) = o;
  }
}

// -------------------------------------------------------------- tables ------
__global__ __launch_bounds__(256) void freq_tab_k(float* __restrict__ tab) {
  const int j = blockIdx.x * 256 + threadIdx.x;
  if (j < 2048) tab[j] = (float)pow(10000.0, (double)j / 2048.0);
}

// ----------------------------------------------------------------- RoPE -----
__global__ __launch_bounds__(256) void rope_qk(f16* __restrict__ q,
                                               f16* __restrict__ k,
                                               const float* __restrict__ ftab,
                                               int E) {
  const int idx = blockIdx.x * 256 + threadIdx.x;
  const int cpr = E / 8;
  const int pos = idx / cpr;
  const int ch = idx % cpr;
  const int j0 = ch * 4;
  const float fpos = (float)pos;
  f16x8 qv = *(f16x8*)(q + (size_t)idx * 8);
  f16x8 kv = *(f16x8*)(k + (size_t)idx * 8);
  f16x8 qo, ko;
#pragma unroll
  for (int p = 0; p < 4; ++p) {
    const int j = j0 + p;
    const float th = fpos / ftab[j];
    float sn, cs;
    sincosf(th, &sn, &cs);
    const f16 c16 = (f16)cs, s16 = (f16)sn;
    const float c = (float)c16, s = (float)s16;
    {
      const float e = (float)qv[2 * p], o = (float)qv[2 * p + 1];
      const f16 t1 = (f16)(e * c), t2 = (f16)(o * s);
      const f16 u1 = (f16)(-(e * s)), u2 = (f16)(o * c);
      qo[2 * p] = (f16)((float)t1 + (float)t2);
      qo[2 * p + 1] = (f16)((float)u1 + (float)u2);
    }
    {
      const float e = (float)kv[2 * p], o = (float)kv[2 * p + 1];
      const f16 t1 = (f16)(e * c), t2 = (f16)(o * s);
      const f16 u1 = (f16)(-(e * s)), u2 = (f16)(o * c);
      ko[2 * p] = (f16)((float)t1 + (float)t2);
      ko[2 * p + 1] = (f16)((float)u1 + (float)u2);
    }
  }
  *(f16x8*)(q + (size_t)idx * 8) = qo;
  *(f16x8*)(k + (size_t)idx * 8) = ko;
}

// ------------------------------------------------------- causal softmax -----
__global__ __launch_bounds__(256) void softmax_causal(f16* __restrict__ sc, int S) {
  const int row = blockIdx.x;
  const int t = threadIdx.x;
  f16* p = sc + (size_t)row * S;
  const int cend = (row & ~255) + 256;
  float v[16];
  bool msk[16];
  bool act[2];
#pragma unroll
  for (int i = 0; i < 2; ++i) {
    act[i] = ((i * 256 + t) * 8) < cend;
    if (act[i]) {
      f16x8 a = *(const f16x8*)(p + (size_t)(i * 256 + t) * 8);
#pragma unroll
      for (int j = 0; j < 8; ++j) v[i * 8 + j] = (float)a[j];
    }
  }
  float m = -1e30f;
#pragma unroll
  for (int i = 0; i < 2; ++i)
    if (act[i])
#pragma unroll
      for (int j = 0; j < 8; ++j) {
        const int col = (i * 256 + t) * 8 + j;
        const int ii = i * 8 + j;
        msk[ii] = (col > row);
        if (!msk[ii]) m = fmaxf(m, v[ii]);
      }
#pragma unroll
  for (int o = 1; o < 64; o <<= 1) m = fmaxf(m, __shfl_xor(m, o));
  __shared__ float red[4];
  const int wid = t >> 6, lane = t & 63;
  if (lane == 0) red[wid] = m;
  __syncthreads();
  m = fmaxf(fmaxf(red[0], red[1]), fmaxf(red[2], red[3]));
  __syncthreads();
  f16 e16[16];
  float sum = 0.f;
#pragma unroll
  for (int i = 0; i < 2; ++i)
    if (act[i])
#pragma unroll
      for (int j = 0; j < 8; ++j) {
        const int ii = i * 8 + j;
        if (msk[ii]) {
          e16[ii] = (f16)0.0f;
        } else {
          const f16 d16 = (f16)(v[ii] - m);
          e16[ii] = (f16)expf((float)d16);
          sum += (float)e16[ii];
        }
      }
#pragma unroll
  for (int o = 1; o < 64; o <<= 1) sum += __shfl_xor(sum, o);
  if (lane == 0) red[wid] = sum;
  __syncthreads();
  sum = red[0] + red[1] + red[2] + red[3];
  const f16 den16 = (f16)sum;
  const float den = (float)den16;
#pragma unroll
  for (int i = 0; i < 2; ++i) {
    if (!act[i]) continue;
    f16x8 o;
#pragma unroll
    for (int j = 0; j < 8; ++j) {
      const int ii = i * 8 + j;
      o[j] = msk[ii] ? (f16)0.0f : (f16)((float)e16[ii] / den);
    }
    *(f16x8*)(p + (size_t)(i * 256 + t) * 8) = o;
  }
}

// ----------------------------------------------- 256^2 deep-pipeline GEMM ---
// r13 sync skeleton; reads rebalanced:
//  ph0: seam{vmcnt(4|0);bar}; stage; tail Q11(T-1).        (0 reads)
//  ph1: b1r(4); stage; Q00 (afr0/b0r read at T-1 ph3).
//  ph2: vmcnt(4) [publishes next-buf h0/h1]; bar; afr1(8); stage; Q01.
//  ph3: stage; Q10; then lookahead afr0/b0r(12) from lds[cur^1] (guarded).
// Prologue: 6 half-stages; vmcnt(8); bar; read tile-0 afr0/b0r.
__device__ __forceinline__ void store_out(f16* p, f16 v) { *p = v; }
__device__ __forceinline__ void store_out(float* p, f16 v) { *p = (float)v; }

template <typename OUT, int MODE>
__global__ __launch_bounds__(512, 2) void gemm256(const f16* __restrict__ A,
                                                  const f16* __restrict__ BT,
                                                  OUT* __restrict__ C,
                                                  int M, int N, int K, float alpha) {
  if (MODE == 1 && blockIdx.x > blockIdx.y) return;
  const int bm = blockIdx.y * 256, bn = blockIdx.x * 256;
  const int kend = (MODE == 2) ? (bm + 256 < K ? bm + 256 : K) : K;
  const int nt = kend >> 6;

  extern __shared__ char smem[];
  f16(*lds)[2][256][64] = (f16(*)[2][256][64])smem;  // [buf][A/B][row][col]

  const int tid = threadIdx.x;
  const int lane = tid & 63;
  const int wid = tid >> 6;          // 0..7
  const int wr = wid >> 2;           // 0..1 (M)
  const int wc = wid & 3;            // 0..3 (N)
  const f16* Ab = A + (size_t)bm * K;
  const f16* Bb = BT + (size_t)bn * K;

  const int l8 = lane >> 3;                                 // 0..7
  const int gxor8 = ((lane & 7) ^ l8) * 8;                  // staged source col
  const int lr = lane & 15;
  const int shi = lane >> 4;                                // 0..3
  const int rsw = lr & 7;                                   // read XOR key

  auto STAGE_P = [&](int p) {
    const int c = p + 6;
    const int Ts = c >> 2, hh = c & 3;
    if (Ts >= nt) return;
    const int k0 = Ts << 6;
    const int bsel = Ts & 1;
#pragma unroll
    for (int l = 0; l < 2; ++l) {
      const int rih0 = wid * 16 + l * 8;
      if (hh == 0 || hh == 3) {  // A halves (qm0 / qm1 rows)
        const int row0 = (rih0 & 63) + ((rih0 >> 6) << 7) + ((hh == 3) ? 64 : 0);
        gload_lds16(Ab + (size_t)(row0 + l8) * K + k0 + gxor8,
                    &lds[bsel][0][row0][0]);
      } else {                   // B halves (qn0 / qn1 rows)
        const int row0 = (rih0 & 31) + ((rih0 >> 5) << 6) + ((hh == 2) ? 32 : 0);
        gload_lds16(Bb + (size_t)(row0 + l8) * K + k0 + gxor8,
                    &lds[bsel][1][row0][0]);
      }
    }
  };

  f32x4 acc[8][4] = {};
  f16x8 afr0[4][2], afr1[4][2], b0r[2][2], b1r[2][2];

#pragma unroll
  for (int p = -6; p < 0; ++p) STAGE_P(p);

  // prologue: publish tile-0 h0/h1 (own vmcnt + barrier), read afr0/b0r.
  asm volatile("s_waitcnt vmcnt(8)" ::: "memory");
  __builtin_amdgcn_sched_barrier(0);
  __builtin_amdgcn_s_barrier();
  __builtin_amdgcn_sched_barrier(0);
#pragma unroll
  for (int m2 = 0; m2 < 4; ++m2)
#pragma unroll
    for (int kk = 0; kk < 2; ++kk)
      afr0[m2][kk] = *(const f16x8*)&lds[0][0][wr * 128 + m2 * 16 + lr]
                                        [((kk * 4 + shi) ^ rsw) * 8];
#pragma unroll
  for (int n2 = 0; n2 < 2; ++n2)
#pragma unroll
    for (int kk = 0; kk < 2; ++kk)
      b0r[n2][kk] = *(const f16x8*)&lds[0][1][wc * 64 + n2 * 16 + lr]
                                       [((kk * 4 + shi) ^ rsw) * 8];
  __builtin_amdgcn_sched_barrier(0);

  for (int T = 0; T < nt; ++T) {
    const int cur = T & 1;
    // ---- ph0: seam; stage; tail MFMA Q11(T-1) (no reads) ----
    __builtin_amdgcn_sched_barrier(0);
    if (T + 1 < nt) {
      asm volatile("s_waitcnt vmcnt(4)" ::: "memory");
    } else {
      asm volatile("s_waitcnt vmcnt(0)" ::: "memory");
    }
    __builtin_amdgcn_sched_barrier(0);
    __builtin_amdgcn_s_barrier();
    __builtin_amdgcn_sched_barrier(0);
    STAGE_P(4 * T);
    __builtin_amdgcn_sched_barrier(0);
    if (T > 0) {
      __builtin_amdgcn_s_setprio(1);
#pragma unroll
      for (int m2 = 0; m2 < 4; ++m2)
#pragma unroll
        for (int n2 = 0; n2 < 2; ++n2)
#pragma unroll
          for (int kk = 0; kk < 2; ++kk)
            acc[4 + m2][2 + n2] = __builtin_amdgcn_mfma_f32_16x16x32_f16(
                afr1[m2][kk], b1r[n2][kk], acc[4 + m2][2 + n2], 0, 0, 0);
      __builtin_amdgcn_s_setprio(0);
    }
    __builtin_amdgcn_sched_barrier(0);
    // ---- ph1: b1r reads; stage; MFMA Q00 ----
#pragma unroll
    for (int n2 = 0; n2 < 2; ++n2)
#pragma unroll
      for (int kk = 0; kk < 2; ++kk)
        b1r[n2][kk] = *(const f16x8*)&lds[cur][1][wc * 64 + 32 + n2 * 16 + lr]
                                         [((kk * 4 + shi) ^ rsw) * 8];
    STAGE_P(4 * T + 1);
    __builtin_amdgcn_sched_barrier(0);
    __builtin_amdgcn_s_setprio(1);
#pragma unroll
    for (int m2 = 0; m2 < 4; ++m2)
#pragma unroll
      for (int n2 = 0; n2 < 2; ++n2)
#pragma unroll
        for (int kk = 0; kk < 2; ++kk)
          acc[m2][n2] = __builtin_amdgcn_mfma_f32_16x16x32_f16(
              afr0[m2][kk], b0r[n2][kk], acc[m2][n2], 0, 0, 0);
    __builtin_amdgcn_s_setprio(0);
    __builtin_amdgcn_sched_barrier(0);
    // ---- ph2: vmcnt(4) publish next h0/h1; barrier; afr1 reads; stage; Q01 --
    asm volatile("s_waitcnt vmcnt(4)" ::: "memory");
    __builtin_amdgcn_sched_barrier(0);
    __builtin_amdgcn_s_barrier();
    __builtin_amdgcn_sched_barrier(0);
#pragma unroll
    for (int m2 = 0; m2 < 4; ++m2)
#pragma unroll
      for (int kk = 0; kk < 2; ++kk)
        afr1[m2][kk] = *(const f16x8*)&lds[cur][0][wr * 128 + 64 + m2 * 16 + lr]
                                          [((kk * 4 + shi) ^ rsw) * 8];
    STAGE_P(4 * T + 2);
    __builtin_amdgcn_sched_barrier(0);
    __builtin_amdgcn_s_setprio(1);
#pragma unroll
    for (int m2 = 0; m2 < 4; ++m2)
#pragma unroll
      for (int n2 = 0; n2 < 2; ++n2)
#pragma unroll
        for (int kk = 0; kk < 2; ++kk)
          acc[m2][2 + n2] = __builtin_amdgcn_mfma_f32_16x16x32_f16(
              afr0[m2][kk], b1r[n2][kk], acc[m2][2 + n2], 0, 0, 0);
    __builtin_amdgcn_s_setprio(0);
    __builtin_amdgcn_sched_barrier(0);
    // ---- ph3: stage; MFMA Q10; then lookahead afr0/b0r (next buffer) ----
    STAGE_P(4 * T + 3);
    __builtin_amdgcn_sched_barrier(0);
    __builtin_amdgcn_s_setprio(1);
#pragma unroll
    for (int m2 = 0; m2 < 4; ++m2)
#pragma unroll
      for (int n2 = 0; n2 < 2; ++n2)
#pragma unroll
        for (int kk = 0; kk < 2; ++kk)
          acc[4 + m2][n2] = __builtin_amdgcn_mfma_f32_16x16x32_f16(
              afr1[m2][kk], b0r[n2][kk], acc[4 + m2][n2], 0, 0, 0);
    __builtin_amdgcn_s_setprio(0);
    __builtin_amdgcn_sched_barrier(0);
    if (T + 1 < nt) {
      const int nxt = cur ^ 1;
#pragma unroll
      for (int m2 = 0; m2 < 4; ++m2)
#pragma unroll
        for (int kk = 0; kk < 2; ++kk)
          afr0[m2][kk] = *(const f16x8*)&lds[nxt][0][wr * 128 + m2 * 16 + lr]
                                            [((kk * 4 + shi) ^ rsw) * 8];
#pragma unroll
      for (int n2 = 0; n2 < 2; ++n2)
#pragma unroll
        for (int kk = 0; kk < 2; ++kk)
          b0r[n2][kk] = *(const f16x8*)&lds[nxt][1][wc * 64 + n2 * 16 + lr]
                                           [((kk * 4 + shi) ^ rsw) * 8];
    }
    __builtin_amdgcn_sched_barrier(0);
  }
  // epilogue: final Q11
  __builtin_amdgcn_s_setprio(1);
#pragma unroll
  for (int m2 = 0; m2 < 4; ++m2)
#pragma unroll
    for (int n2 = 0; n2 < 2; ++n2)
#pragma unroll
      for (int kk = 0; kk < 2; ++kk)
        acc[4 + m2][2 + n2] = __builtin_amdgcn_mfma_f32_16x16x32_f16(
            afr1[m2][kk], b1r[n2][kk], acc[4 + m2][2 + n2], 0, 0, 0);
  __builtin_amdgcn_s_setprio(0);

  const int rb_l = wr * 128 + (lane >> 4) * 4;
  const int cb_l = wc * 64 + (lane & 15);

  if (MODE == 4) {
    // transposed store: C[bn+col][bm+row], C row-stride = M.
    f16* tl = (f16*)smem;  // [256 cols][stride 258]
    asm volatile("s_waitcnt lgkmcnt(0)" ::: "memory");
    __builtin_amdgcn_s_barrier();  // all waves done with K-loop LDS
#pragma unroll
    for (int mm = 0; mm < 8; ++mm)
#pragma unroll
      for (int nn = 0; nn < 4; ++nn) {
        const int c = cb_l + nn * 16;
#pragma unroll
        for (int r = 0; r < 4; ++r)
          tl[(size_t)c * 258 + rb_l + mm * 16 + r] = (f16)acc[mm][nn][r];
      }
    asm volatile("s_waitcnt lgkmcnt(0)" ::: "memory");
    __builtin_amdgcn_s_barrier();
    const int c = tid >> 1, hf = tid & 1;  // col 0..255, half 0/1
#pragma unroll
    for (int i = 0; i < 16; ++i) {
      f16x8 v8 = *(const f16x8*)&tl[(size_t)c * 258 + hf * 128 + i * 8];
      *(f16x8*)((f16*)C + (size_t)(bn + c) * M + bm + hf * 128 + i * 8) = v8;
    }
    return;
  }

#pragma unroll
  for (int mm = 0; mm < 8; ++mm)
#pragma unroll
    for (int nn = 0; nn < 4; ++nn) {
      const int col = bn + cb_l + nn * 16;
#pragma unroll
      for (int r = 0; r < 4; ++r) {
        f16 h = (f16)acc[mm][nn][r];
        if (alpha != 1.0f) h = (f16)((float)h * alpha);
        store_out(&C[(size_t)(bm + rb_l + mm * 16 + r) * N + col], h);
      }
    }
}

// ---------------------------------------------------------------- launch ----
// d_out = FLOAT32 (64MiB). vT staged there as f16 (32MiB), dead before final.
// ws: 4 slots x 32MiB: s0 xq; s1 wT->ftab->sc; s2 q->attn; s3 k->wT2.
extern "C" void kernel_launch(void* const* d_in, const int* in_sizes, int n_in,
                              void* d_out, int out_size, void* d_ws, size_t ws_size,
                              hipStream_t stream) {
  const float* x = (const float*)d_in[0];
  const float* wq = (const float*)d_in[1];
  const float* wk = (const float*)d_in[2];
  const float* wv = (const float*)d_in[3];
  const float* wo = (const float*)d_in[4];
  const float* sf = (const float*)d_in[5];
  float* out = (float*)d_out;

  const int S = S_DIM, E = E_DIM;
  const size_t U = (size_t)S * E * sizeof(f16);  // 32 MiB
  char* ws = (char*)d_ws;
  f16* xq = (f16*)(ws + 0 * U);
  f16* wT = (f16*)(ws + 1 * U);
  f16* q  = (f16*)(ws + 2 * U);
  f16* k  = (f16*)(ws + 3 * U);
  f16* vT = (f16*)d_out;  // written transposed by the v-GEMM (MODE 4)

  const int LDSA = 131072;  // K-loop only (plain/causal/PV instantiations)
  const int LDSB = 135168;  // K-loop + 256*258*2 transpose bounce (MODE 4)
  hipFuncSetAttribute(reinterpret_cast<const void*>(&gemm256<f16, 0>),
                      hipFuncAttributeMaxDynamicSharedMemorySize, LDSA);
  hipFuncSetAttribute(reinterpret_cast<const void*>(&gemm256<f16, 1>),
                      hipFuncAttributeMaxDynamicSharedMemorySize, LDSA);
  hipFuncSetAttribute(reinterpret_cast<const void*>(&gemm256<f16, 2>),
                      hipFuncAttributeMaxDynamicSharedMemorySize, LDSA);
  hipFuncSetAttribute(reinterpret_cast<const void*>(&gemm256<f16, 4>),
                      hipFuncAttributeMaxDynamicSharedMemorySize, LDSB);
  hipFuncSetAttribute(reinterpret_cast<const void*>(&gemm256<float, 0>),
                      hipFuncAttributeMaxDynamicSharedMemorySize, LDSA);

  dim3 b256(256), b512(512);
  dim3 gT(E / 64, E / 64);
  dim3 gG(E / 256, S / 256);

  rmsnorm_f16<<<S, b256, 0, stream>>>(x, xq, E);

  wconv_t<<<gT, b256, 0, stream>>>(wq, sf, wT, E);
  gemm256<f16, 0><<<gG, b512, LDSA, stream>>>(xq, wT, q, S, E, E, 1.0f);
  wconv_t<<<gT, b256, 0, stream>>>(wk, sf, wT, E);
  gemm256<f16, 0><<<gG, b512, LDSA, stream>>>(xq, wT, k, S, E, E, 1.0f);
  wconv_t<<<gT, b256, 0, stream>>>(wv, sf, wT, E);
  gemm256<f16, 4><<<gG, b512, LDSB, stream>>>(xq, wT, vT, S, E, E, 1.0f);

  float* ftab = (float*)wT;
  freq_tab_k<<<8, b256, 0, stream>>>(ftab);
  rope_qk<<<(S * (E / 8)) / 256, b256, 0, stream>>>(q, k, ftab, E);

  f16* sc = wT;
  gemm256<f16, 1><<<dim3(S / 256, S / 256), b512, LDSA, stream>>>(q, k, sc, S, S,
                                                                  E, 1.0f / 64.0f);
  softmax_causal<<<S, b256, 0, stream>>>(sc, S);

  f16* attn = q;
  gemm256<f16, 2><<<gG, b512, LDSA, stream>>>(sc, vT, attn, S, E, S, 1.0f);

  f16* wT2 = k;
  wconv_t<<<gT, b256, 0, stream>>>(wo, (const float*)nullptr, wT2, E);
  gemm256<float, 0><<<gG, b512, LDSA, stream>>>(attn, wT2, out, S, E, E, 1.0f);
}

// Round 20
// 789.045 us; speedup vs baseline: 1.0048x; 1.0048x over previous
//
#include <hip/hip_runtime.h>
#include <hip/hip_bf16.h>
#include <cmath>

// ATTNLayer fused pipeline, S=E=4096.
// Round 20: r18 base (792.2us) with (1) setprio REMOVED from gemm256
// (isolated A/B; m190 precedent: setprio hurts lockstep schedules) and
// (2) freq_tab fused into rmsnorm (ftab -> d_out+48MiB scratch).

typedef _Float16 f16;
typedef _Float16 f16x4 __attribute__((ext_vector_type(4)));
typedef _Float16 f16x8 __attribute__((ext_vector_type(8)));
typedef float f32x4 __attribute__((ext_vector_type(4)));

#define S_DIM 4096
#define E_DIM 4096

__device__ __forceinline__ void gload_lds16(const void* g, void* l) {
  __builtin_amdgcn_global_load_lds((const __attribute__((address_space(1))) void*)g,
                                   (__attribute__((address_space(3))) void*)l,
                                   16, 0, 0);
}

// ------------------------------------------------- RMSNorm (+freq table) ----
__global__ __launch_bounds__(256) void rmsnorm_f16(const float* __restrict__ x,
                                                   f16* __restrict__ xq,
                                                   float* __restrict__ ftab,
                                                   int E) {
  const int row = blockIdx.x;
  const int t = threadIdx.x;
  // blocks 0..7 additionally fill the RoPE freq table (2048 entries)
  if (row < 8) {
    const int j = row * 256 + t;
    ftab[j] = (float)pow(10000.0, (double)j / 2048.0);
  }
  const float4* xr = (const float4*)(x + (size_t)row * E);
  float4 v[4];
  float ss = 0.f;
#pragma unroll
  for (int i = 0; i < 4; ++i) {
    v[i] = xr[t + 256 * i];
    ss += v[i].x * v[i].x + v[i].y * v[i].y + v[i].z * v[i].z + v[i].w * v[i].w;
  }
#pragma unroll
  for (int o = 1; o < 64; o <<= 1) ss += __shfl_xor(ss, o);
  __shared__ float red[4];
  const int wid = t >> 6, lane = t & 63;
  if (lane == 0) red[wid] = ss;
  __syncthreads();
  const float tot = red[0] + red[1] + red[2] + red[3];
  const float r = 1.0f / sqrtf(tot / (float)E + 1e-6f);
  f16* xo = xq + (size_t)row * E;
#pragma unroll
  for (int i = 0; i < 4; ++i) {
    f16x4 o;
    o[0] = (f16)(v[i].x * r);
    o[1] = (f16)(v[i].y * r);
    o[2] = (f16)(v[i].z * r);
    o[3] = (f16)(v[i].w * r);
    *(f16x4*)(xo + 4 * (t + 256 * i)) = o;
  }
}

// ------------------------------------------- weight convert + transpose -----
__global__ __launch_bounds__(256) void wconv_t(const float* __restrict__ W,
                                               const float* __restrict__ s,
                                               f16* __restrict__ WT, int N) {
  __shared__ f16 tile[64][65];
  const int tr = blockIdx.y * 64;  // e base
  const int tc = blockIdx.x * 64;  // n base
  const int t = threadIdx.x;
  const int r = t / 16;
  const int c4 = (t % 16) * 4;
#pragma unroll
  for (int i = 0; i < 4; ++i) {
    const int row = r + i * 16;
    float4 w = *(const float4*)(W + (size_t)(tr + row) * N + tc + c4);
    const float sc = s ? s[tr + row] : 1.0f;
    tile[row][c4 + 0] = (f16)(w.x * sc);
    tile[row][c4 + 1] = (f16)(w.y * sc);
    tile[row][c4 + 2] = (f16)(w.z * sc);
    tile[row][c4 + 3] = (f16)(w.w * sc);
  }
  __syncthreads();
#pragma unroll
  for (int i = 0; i < 4; ++i) {
    const int row = r + i * 16;
    f16x4 o;
    o[0] = tile[c4 + 0][row];
    o[1] = tile[c4 + 1][row];
    o[2] = tile[c4 + 2][row];
    o[3] = tile[c4 + 3][row];
    *(f16x4*)(WT + (size_t)(tc + row) * N + tr + c4) = o;
  }
}

// ----------------------------------------------------------------- RoPE -----
__global__ __launch_bounds__(256) void rope_qk(f16* __restrict__ q,
                                               f16* __restrict__ k,
                                               const float* __restrict__ ftab,
                                               int E) {
  const int idx = blockIdx.x * 256 + threadIdx.x;
  const int cpr = E / 8;
  const int pos = idx / cpr;
  const int ch = idx % cpr;
  const int j0 = ch * 4;
  const float fpos = (float)pos;
  f16x8 qv = *(f16x8*)(q + (size_t)idx * 8);
  f16x8 kv = *(f16x8*)(k + (size_t)idx * 8);
  f16x8 qo, ko;
#pragma unroll
  for (int p = 0; p < 4; ++p) {
    const int j = j0 + p;
    const float th = fpos / ftab[j];
    float sn, cs;
    sincosf(th, &sn, &cs);
    const f16 c16 = (f16)cs, s16 = (f16)sn;
    const float c = (float)c16, s = (float)s16;
    {
      const float e = (float)qv[2 * p], o = (float)qv[2 * p + 1];
      const f16 t1 = (f16)(e * c), t2 = (f16)(o * s);
      const f16 u1 = (f16)(-(e * s)), u2 = (f16)(o * c);
      qo[2 * p] = (f16)((float)t1 + (float)t2);
      qo[2 * p + 1] = (f16)((float)u1 + (float)u2);
    }
    {
      const float e = (float)kv[2 * p], o = (float)kv[2 * p + 1];
      const f16 t1 = (f16)(e * c), t2 = (f16)(o * s);
      const f16 u1 = (f16)(-(e * s)), u2 = (f16)(o * c);
      ko[2 * p] = (f16)((float)t1 + (float)t2);
      ko[2 * p + 1] = (f16)((float)u1 + (float)u2);
    }
  }
  *(f16x8*)(q + (size_t)idx * 8) = qo;
  *(f16x8*)(k + (size_t)idx * 8) = ko;
}

// ------------------------------------------------------- causal softmax -----
__global__ __launch_bounds__(256) void softmax_causal(f16* __restrict__ sc, int S) {
  const int row = blockIdx.x;
  const int t = threadIdx.x;
  f16* p = sc + (size_t)row * S;
  const int cend = (row & ~255) + 256;
  float v[16];
  bool msk[16];
  bool act[2];
#pragma unroll
  for (int i = 0; i < 2; ++i) {
    act[i] = ((i * 256 + t) * 8) < cend;
    if (act[i]) {
      f16x8 a = *(const f16x8*)(p + (size_t)(i * 256 + t) * 8);
#pragma unroll
      for (int j = 0; j < 8; ++j) v[i * 8 + j] = (float)a[j];
    }
  }
  float m = -1e30f;
#pragma unroll
  for (int i = 0; i < 2; ++i)
    if (act[i])
#pragma unroll
      for (int j = 0; j < 8; ++j) {
        const int col = (i * 256 + t) * 8 + j;
        const int ii = i * 8 + j;
        msk[ii] = (col > row);
        if (!msk[ii]) m = fmaxf(m, v[ii]);
      }
#pragma unroll
  for (int o = 1; o < 64; o <<= 1) m = fmaxf(m, __shfl_xor(m, o));
  __shared__ float red[4];
  const int wid = t >> 6, lane = t & 63;
  if (lane == 0) red[wid] = m;
  __syncthreads();
  m = fmaxf(fmaxf(red[0], red[1]), fmaxf(red[2], red[3]));
  __syncthreads();
  f16 e16[16];
  float sum = 0.f;
#pragma unroll
  for (int i = 0; i < 2; ++i)
    if (act[i])
#pragma unroll
      for (int j = 0; j < 8; ++j) {
        const int ii = i * 8 + j;
        if (msk[ii]) {
          e16[ii] = (f16)0.0f;
        } else {
          const f16 d16 = (f16)(v[ii] - m);
          e16[ii] = (f16)expf((float)d16);
          sum += (float)e16[ii];
        }
      }
#pragma unroll
  for (int o = 1; o < 64; o <<= 1) sum += __shfl_xor(sum, o);
  if (lane == 0) red[wid] = sum;
  __syncthreads();
  sum = red[0] + red[1] + red[2] + red[3];
  const f16 den16 = (f16)sum;
  const float den = (float)den16;
#pragma unroll
  for (int i = 0; i < 2; ++i) {
    if (!act[i]) continue;
    f16x8 o;
#pragma unroll
    for (int j = 0; j < 8; ++j) {
      const int ii = i * 8 + j;
      o[j] = msk[ii] ? (f16)0.0f : (f16)((float)e16[ii] / den);
    }
    *(f16x8*)(p + (size_t)(i * 256 + t) * 8) = o;
  }
}

// ----------------------------------------------- 256^2 deep-pipeline GEMM ---
// r13 fragment-pipelined K-loop, setprio removed (A/B). MODE template:
// 0 plain, 1 causal skip, 2 PV K-cap, 4 transposed store (LDS bounce).
__device__ __forceinline__ void store_out(f16* p, f16 v) { *p = v; }
__device__ __forceinline__ void store_out(float* p, f16 v) { *p = (float)v; }

template <typename OUT, int MODE>
__global__ __launch_bounds__(512, 2) void gemm256(const f16* __restrict__ A,
                                                  const f16* __restrict__ BT,
                                                  OUT* __restrict__ C,
                                                  int M, int N, int K, float alpha) {
  if (MODE == 1 && blockIdx.x > blockIdx.y) return;
  const int bm = blockIdx.y * 256, bn = blockIdx.x * 256;
  const int kend = (MODE == 2) ? (bm + 256 < K ? bm + 256 : K) : K;
  const int nt = kend >> 6;

  extern __shared__ char smem[];
  f16(*lds)[2][256][64] = (f16(*)[2][256][64])smem;  // [buf][A/B][row][col]

  const int tid = threadIdx.x;
  const int lane = tid & 63;
  const int wid = tid >> 6;          // 0..7
  const int wr = wid >> 2;           // 0..1 (M)
  const int wc = wid & 3;            // 0..3 (N)
  const f16* Ab = A + (size_t)bm * K;
  const f16* Bb = BT + (size_t)bn * K;

  const int l8 = lane >> 3;                                 // 0..7
  const int gxor8 = ((lane & 7) ^ l8) * 8;                  // staged source col
  const int lr = lane & 15;
  const int shi = lane >> 4;                                // 0..3
  const int rsw = lr & 7;                                   // read XOR key

  auto STAGE_P = [&](int p) {
    const int c = p + 6;
    const int Ts = c >> 2, hh = c & 3;
    if (Ts >= nt) return;
    const int k0 = Ts << 6;
    const int bsel = Ts & 1;
#pragma unroll
    for (int l = 0; l < 2; ++l) {
      const int rih0 = wid * 16 + l * 8;
      if (hh == 0 || hh == 3) {  // A halves (qm0 / qm1 rows)
        const int row0 = (rih0 & 63) + ((rih0 >> 6) << 7) + ((hh == 3) ? 64 : 0);
        gload_lds16(Ab + (size_t)(row0 + l8) * K + k0 + gxor8,
                    &lds[bsel][0][row0][0]);
      } else {                   // B halves (qn0 / qn1 rows)
        const int row0 = (rih0 & 31) + ((rih0 >> 5) << 6) + ((hh == 2) ? 32 : 0);
        gload_lds16(Bb + (size_t)(row0 + l8) * K + k0 + gxor8,
                    &lds[bsel][1][row0][0]);
      }
    }
  };

  f32x4 acc[8][4] = {};
  f16x8 afr0[4][2], afr1[4][2], b0r[2][2], b1r[2][2];

#pragma unroll
  for (int p = -6; p < 0; ++p) STAGE_P(p);

  for (int T = 0; T < nt; ++T) {
    const int cur = T & 1;
    // ---- ph0: seam; S0 reads; stage; tail MFMA Q11(T-1) ----
    __builtin_amdgcn_sched_barrier(0);
    if (T + 1 < nt) {
      asm volatile("s_waitcnt vmcnt(4)" ::: "memory");
    } else {
      asm volatile("s_waitcnt vmcnt(0)" ::: "memory");
    }
    __builtin_amdgcn_sched_barrier(0);
    __builtin_amdgcn_s_barrier();
    __builtin_amdgcn_sched_barrier(0);
#pragma unroll
    for (int m2 = 0; m2 < 4; ++m2)
#pragma unroll
      for (int kk = 0; kk < 2; ++kk)
        afr0[m2][kk] = *(const f16x8*)&lds[cur][0][wr * 128 + m2 * 16 + lr]
                                          [((kk * 4 + shi) ^ rsw) * 8];
#pragma unroll
    for (int n2 = 0; n2 < 2; ++n2)
#pragma unroll
      for (int kk = 0; kk < 2; ++kk)
        b0r[n2][kk] = *(const f16x8*)&lds[cur][1][wc * 64 + n2 * 16 + lr]
                                         [((kk * 4 + shi) ^ rsw) * 8];
    STAGE_P(4 * T);
    __builtin_amdgcn_sched_barrier(0);
    if (T > 0) {
#pragma unroll
      for (int m2 = 0; m2 < 4; ++m2)
#pragma unroll
        for (int n2 = 0; n2 < 2; ++n2)
#pragma unroll
          for (int kk = 0; kk < 2; ++kk)
            acc[4 + m2][2 + n2] = __builtin_amdgcn_mfma_f32_16x16x32_f16(
                afr1[m2][kk], b1r[n2][kk], acc[4 + m2][2 + n2], 0, 0, 0);
    }
    __builtin_amdgcn_sched_barrier(0);
    // ---- ph1: S1 reads; stage; MFMA Q00 ----
#pragma unroll
    for (int n2 = 0; n2 < 2; ++n2)
#pragma unroll
      for (int kk = 0; kk < 2; ++kk)
        b1r[n2][kk] = *(const f16x8*)&lds[cur][1][wc * 64 + 32 + n2 * 16 + lr]
                                         [((kk * 4 + shi) ^ rsw) * 8];
    STAGE_P(4 * T + 1);
    __builtin_amdgcn_sched_barrier(0);
#pragma unroll
    for (int m2 = 0; m2 < 4; ++m2)
#pragma unroll
      for (int n2 = 0; n2 < 2; ++n2)
#pragma unroll
        for (int kk = 0; kk < 2; ++kk)
          acc[m2][n2] = __builtin_amdgcn_mfma_f32_16x16x32_f16(
              afr0[m2][kk], b0r[n2][kk], acc[m2][n2], 0, 0, 0);
    __builtin_amdgcn_sched_barrier(0);
    // ---- ph2: safety barrier; S2 reads; stage; MFMA Q01 ----
    __builtin_amdgcn_s_barrier();
    __builtin_amdgcn_sched_barrier(0);
#pragma unroll
    for (int m2 = 0; m2 < 4; ++m2)
#pragma unroll
      for (int kk = 0; kk < 2; ++kk)
        afr1[m2][kk] = *(const f16x8*)&lds[cur][0][wr * 128 + 64 + m2 * 16 + lr]
                                          [((kk * 4 + shi) ^ rsw) * 8];
    STAGE_P(4 * T + 2);
    __builtin_amdgcn_sched_barrier(0);
#pragma unroll
    for (int m2 = 0; m2 < 4; ++m2)
#pragma unroll
      for (int n2 = 0; n2 < 2; ++n2)
#pragma unroll
        for (int kk = 0; kk < 2; ++kk)
          acc[m2][2 + n2] = __builtin_amdgcn_mfma_f32_16x16x32_f16(
              afr0[m2][kk], b1r[n2][kk], acc[m2][2 + n2], 0, 0, 0);
    __builtin_amdgcn_sched_barrier(0);
    // ---- ph3: stage; MFMA Q10 ----
    STAGE_P(4 * T + 3);
    __builtin_amdgcn_sched_barrier(0);
#pragma unroll
    for (int m2 = 0; m2 < 4; ++m2)
#pragma unroll
      for (int n2 = 0; n2 < 2; ++n2)
#pragma unroll
        for (int kk = 0; kk < 2; ++kk)
          acc[4 + m2][n2] = __builtin_amdgcn_mfma_f32_16x16x32_f16(
              afr1[m2][kk], b0r[n2][kk], acc[4 + m2][n2], 0, 0, 0);
  }
  // epilogue: final Q11
#pragma unroll
  for (int m2 = 0; m2 < 4; ++m2)
#pragma unroll
    for (int n2 = 0; n2 < 2; ++n2)
#pragma unroll
      for (int kk = 0; kk < 2; ++kk)
        acc[4 + m2][2 + n2] = __builtin_amdgcn_mfma_f32_16x16x32_f16(
            afr1[m2][kk], b1r[n2][kk], acc[4 + m2][2 + n2], 0, 0, 0);

  const int rb_l = wr * 128 + (lane >> 4) * 4;
  const int cb_l = wc * 64 + (lane & 15);

  if (MODE == 4) {
    // transposed store: C[bn+col][bm+row], C row-stride = M.
    f16* tl = (f16*)smem;  // [256 cols][stride 258]
    asm volatile("s_waitcnt lgkmcnt(0)" ::: "memory");
    __builtin_amdgcn_s_barrier();  // all waves done with K-loop LDS
#pragma unroll
    for (int mm = 0; mm < 8; ++mm)
#pragma unroll
      for (int nn = 0; nn < 4; ++nn) {
        const int c = cb_l + nn * 16;
#pragma unroll
        for (int r = 0; r < 4; ++r)
          tl[(size_t)c * 258 + rb_l + mm * 16 + r] = (f16)acc[mm][nn][r];
      }
    asm volatile("s_waitcnt lgkmcnt(0)" ::: "memory");
    __builtin_amdgcn_s_barrier();
    const int c = tid >> 1, hf = tid & 1;  // col 0..255, half 0/1
#pragma unroll
    for (int i = 0; i < 16; ++i) {
      f16x8 v8 = *(const f16x8*)&tl[(size_t)c * 258 + hf * 128 + i * 8];
      *(f16x8*)((f16*)C + (size_t)(bn + c) * M + bm + hf * 128 + i * 8) = v8;
    }
    return;
  }

#pragma unroll
  for (int mm = 0; mm < 8; ++mm)
#pragma unroll
    for (int nn = 0; nn < 4; ++nn) {
      const int col = bn + cb_l + nn * 16;
#pragma unroll
      for (int r = 0; r < 4; ++r) {
        f16 h = (f16)acc[mm][nn][r];
        if (alpha != 1.0f) h = (f16)((float)h * alpha);
        store_out(&C[(size_t)(bm + rb_l + mm * 16 + r) * N + col], h);
      }
    }
}

// ---------------------------------------------------------------- launch ----
// d_out = FLOAT32 (64MiB): [0,32MiB) vT staging (f16); +48MiB ftab (8KB);
// all dead before the final f32 overwrite. ws: 4 slots x 32MiB.
extern "C" void kernel_launch(void* const* d_in, const int* in_sizes, int n_in,
                              void* d_out, int out_size, void* d_ws, size_t ws_size,
                              hipStream_t stream) {
  const float* x = (const float*)d_in[0];
  const float* wq = (const float*)d_in[1];
  const float* wk = (const float*)d_in[2];
  const float* wv = (const float*)d_in[3];
  const float* wo = (const float*)d_in[4];
  const float* sf = (const float*)d_in[5];
  float* out = (float*)d_out;

  const int S = S_DIM, E = E_DIM;
  const size_t U = (size_t)S * E * sizeof(f16);  // 32 MiB
  char* ws = (char*)d_ws;
  f16* xq = (f16*)(ws + 0 * U);
  f16* wT = (f16*)(ws + 1 * U);
  f16* q  = (f16*)(ws + 2 * U);
  f16* k  = (f16*)(ws + 3 * U);
  f16* vT = (f16*)d_out;                  // written transposed by v-GEMM
  float* ftab = out + 12 * 1024 * 1024;   // 48MiB offset, 8KB used

  const int LDSA = 131072;
  const int LDSB = 135168;
  hipFuncSetAttribute(reinterpret_cast<const void*>(&gemm256<f16, 0>),
                      hipFuncAttributeMaxDynamicSharedMemorySize, LDSA);
  hipFuncSetAttribute(reinterpret_cast<const void*>(&gemm256<f16, 1>),
                      hipFuncAttributeMaxDynamicSharedMemorySize, LDSA);
  hipFuncSetAttribute(reinterpret_cast<const void*>(&gemm256<f16, 2>),
                      hipFuncAttributeMaxDynamicSharedMemorySize, LDSA);
  hipFuncSetAttribute(reinterpret_cast<const void*>(&gemm256<f16, 4>),
                      hipFuncAttributeMaxDynamicSharedMemorySize, LDSB);
  hipFuncSetAttribute(reinterpret_cast<const void*>(&gemm256<float, 0>),
                      hipFuncAttributeMaxDynamicSharedMemorySize, LDSA);

  dim3 b256(256), b512(512);
  dim3 gT(E / 64, E / 64);
  dim3 gG(E / 256, S / 256);

  rmsnorm_f16<<<S, b256, 0, stream>>>(x, xq, ftab, E);

  wconv_t<<<gT, b256, 0, stream>>>(wq, sf, wT, E);
  gemm256<f16, 0><<<gG, b512, LDSA, stream>>>(xq, wT, q, S, E, E, 1.0f);
  wconv_t<<<gT, b256, 0, stream>>>(wk, sf, wT, E);
  gemm256<f16, 0><<<gG, b512, LDSA, stream>>>(xq, wT, k, S, E, E, 1.0f);
  wconv_t<<<gT, b256, 0, stream>>>(wv, sf, wT, E);
  gemm256<f16, 4><<<gG, b512, LDSB, stream>>>(xq, wT, vT, S, E, E, 1.0f);

  rope_qk<<<(S * (E / 8)) / 256, b256, 0, stream>>>(q, k, ftab, E);

  f16* sc = wT;
  gemm256<f16, 1><<<dim3(S / 256, S / 256), b512, LDSA, stream>>>(q, k, sc, S, S,
                                                                  E, 1.0f / 64.0f);
  softmax_causal<<<S, b256, 0, stream>>>(sc, S);

  f16* attn = q;
  gemm256<f16, 2><<<gG, b512, LDSA, stream>>>(sc, vT, attn, S, E, S, 1.0f);

  f16* wT2 = k;
  wconv_t<<<gT, b256, 0, stream>>>(wo, (const float*)nullptr, wT2, E);
  gemm256<float, 0><<<gG, b512, LDSA, stream>>>(attn, wT2, out, S, E, E, 1.0f);
}

// Round 21
// 779.126 us; speedup vs baseline: 1.0176x; 1.0127x over previous
//
#include <hip/hip_runtime.h>
#include <hip/hip_bf16.h>
#include <cmath>

// ATTNLayer fused pipeline, S=E=4096.
// Round 21: r20 base (789.0us) + V^T computed by OPERAND SWAP
// (vT[n][s] = sum_k wT[n,k] xq[s,k] == gemm256<f16,0>(wT, xq)) --
// mode-4 transpose epilogue deleted (was +8.5us on the v-GEMM).
// Bit-identical accumulation (same k-order; FP mul commutes).

typedef _Float16 f16;
typedef _Float16 f16x4 __attribute__((ext_vector_type(4)));
typedef _Float16 f16x8 __attribute__((ext_vector_type(8)));
typedef float f32x4 __attribute__((ext_vector_type(4)));

#define S_DIM 4096
#define E_DIM 4096

__device__ __forceinline__ void gload_lds16(const void* g, void* l) {
  __builtin_amdgcn_global_load_lds((const __attribute__((address_space(1))) void*)g,
                                   (__attribute__((address_space(3))) void*)l,
                                   16, 0, 0);
}

// ------------------------------------------------- RMSNorm (+freq table) ----
__global__ __launch_bounds__(256) void rmsnorm_f16(const float* __restrict__ x,
                                                   f16* __restrict__ xq,
                                                   float* __restrict__ ftab,
                                                   int E) {
  const int row = blockIdx.x;
  const int t = threadIdx.x;
  if (row < 8) {
    const int j = row * 256 + t;
    ftab[j] = (float)pow(10000.0, (double)j / 2048.0);
  }
  const float4* xr = (const float4*)(x + (size_t)row * E);
  float4 v[4];
  float ss = 0.f;
#pragma unroll
  for (int i = 0; i < 4; ++i) {
    v[i] = xr[t + 256 * i];
    ss += v[i].x * v[i].x + v[i].y * v[i].y + v[i].z * v[i].z + v[i].w * v[i].w;
  }
#pragma unroll
  for (int o = 1; o < 64; o <<= 1) ss += __shfl_xor(ss, o);
  __shared__ float red[4];
  const int wid = t >> 6, lane = t & 63;
  if (lane == 0) red[wid] = ss;
  __syncthreads();
  const float tot = red[0] + red[1] + red[2] + red[3];
  const float r = 1.0f / sqrtf(tot / (float)E + 1e-6f);
  f16* xo = xq + (size_t)row * E;
#pragma unroll
  for (int i = 0; i < 4; ++i) {
    f16x4 o;
    o[0] = (f16)(v[i].x * r);
    o[1] = (f16)(v[i].y * r);
    o[2] = (f16)(v[i].z * r);
    o[3] = (f16)(v[i].w * r);
    *(f16x4*)(xo + 4 * (t + 256 * i)) = o;
  }
}

// ------------------------------------------- weight convert + transpose -----
__global__ __launch_bounds__(256) void wconv_t(const float* __restrict__ W,
                                               const float* __restrict__ s,
                                               f16* __restrict__ WT, int N) {
  __shared__ f16 tile[64][65];
  const int tr = blockIdx.y * 64;  // e base
  const int tc = blockIdx.x * 64;  // n base
  const int t = threadIdx.x;
  const int r = t / 16;
  const int c4 = (t % 16) * 4;
#pragma unroll
  for (int i = 0; i < 4; ++i) {
    const int row = r + i * 16;
    float4 w = *(const float4*)(W + (size_t)(tr + row) * N + tc + c4);
    const float sc = s ? s[tr + row] : 1.0f;
    tile[row][c4 + 0] = (f16)(w.x * sc);
    tile[row][c4 + 1] = (f16)(w.y * sc);
    tile[row][c4 + 2] = (f16)(w.z * sc);
    tile[row][c4 + 3] = (f16)(w.w * sc);
  }
  __syncthreads();
#pragma unroll
  for (int i = 0; i < 4; ++i) {
    const int row = r + i * 16;
    f16x4 o;
    o[0] = tile[c4 + 0][row];
    o[1] = tile[c4 + 1][row];
    o[2] = tile[c4 + 2][row];
    o[3] = tile[c4 + 3][row];
    *(f16x4*)(WT + (size_t)(tc + row) * N + tr + c4) = o;
  }
}

// ----------------------------------------------------------------- RoPE -----
__global__ __launch_bounds__(256) void rope_qk(f16* __restrict__ q,
                                               f16* __restrict__ k,
                                               const float* __restrict__ ftab,
                                               int E) {
  const int idx = blockIdx.x * 256 + threadIdx.x;
  const int cpr = E / 8;
  const int pos = idx / cpr;
  const int ch = idx % cpr;
  const int j0 = ch * 4;
  const float fpos = (float)pos;
  f16x8 qv = *(f16x8*)(q + (size_t)idx * 8);
  f16x8 kv = *(f16x8*)(k + (size_t)idx * 8);
  f16x8 qo, ko;
#pragma unroll
  for (int p = 0; p < 4; ++p) {
    const int j = j0 + p;
    const float th = fpos / ftab[j];
    float sn, cs;
    sincosf(th, &sn, &cs);
    const f16 c16 = (f16)cs, s16 = (f16)sn;
    const float c = (float)c16, s = (float)s16;
    {
      const float e = (float)qv[2 * p], o = (float)qv[2 * p + 1];
      const f16 t1 = (f16)(e * c), t2 = (f16)(o * s);
      const f16 u1 = (f16)(-(e * s)), u2 = (f16)(o * c);
      qo[2 * p] = (f16)((float)t1 + (float)t2);
      qo[2 * p + 1] = (f16)((float)u1 + (float)u2);
    }
    {
      const float e = (float)kv[2 * p], o = (float)kv[2 * p + 1];
      const f16 t1 = (f16)(e * c), t2 = (f16)(o * s);
      const f16 u1 = (f16)(-(e * s)), u2 = (f16)(o * c);
      ko[2 * p] = (f16)((float)t1 + (float)t2);
      ko[2 * p + 1] = (f16)((float)u1 + (float)u2);
    }
  }
  *(f16x8*)(q + (size_t)idx * 8) = qo;
  *(f16x8*)(k + (size_t)idx * 8) = ko;
}

// ------------------------------------------------------- causal softmax -----
__global__ __launch_bounds__(256) void softmax_causal(f16* __restrict__ sc, int S) {
  const int row = blockIdx.x;
  const int t = threadIdx.x;
  f16* p = sc + (size_t)row * S;
  const int cend = (row & ~255) + 256;
  float v[16];
  bool msk[16];
  bool act[2];
#pragma unroll
  for (int i = 0; i < 2; ++i) {
    act[i] = ((i * 256 + t) * 8) < cend;
    if (act[i]) {
      f16x8 a = *(const f16x8*)(p + (size_t)(i * 256 + t) * 8);
#pragma unroll
      for (int j = 0; j < 8; ++j) v[i * 8 + j] = (float)a[j];
    }
  }
  float m = -1e30f;
#pragma unroll
  for (int i = 0; i < 2; ++i)
    if (act[i])
#pragma unroll
      for (int j = 0; j < 8; ++j) {
        const int col = (i * 256 + t) * 8 + j;
        const int ii = i * 8 + j;
        msk[ii] = (col > row);
        if (!msk[ii]) m = fmaxf(m, v[ii]);
      }
#pragma unroll
  for (int o = 1; o < 64; o <<= 1) m = fmaxf(m, __shfl_xor(m, o));
  __shared__ float red[4];
  const int wid = t >> 6, lane = t & 63;
  if (lane == 0) red[wid] = m;
  __syncthreads();
  m = fmaxf(fmaxf(red[0], red[1]), fmaxf(red[2], red[3]));
  __syncthreads();
  f16 e16[16];
  float sum = 0.f;
#pragma unroll
  for (int i = 0; i < 2; ++i)
    if (act[i])
#pragma unroll
      for (int j = 0; j < 8; ++j) {
        const int ii = i * 8 + j;
        if (msk[ii]) {
          e16[ii] = (f16)0.0f;
        } else {
          const f16 d16 = (f16)(v[ii] - m);
          e16[ii] = (f16)expf((float)d16);
          sum += (float)e16[ii];
        }
      }
#pragma unroll
  for (int o = 1; o < 64; o <<= 1) sum += __shfl_xor(sum, o);
  if (lane == 0) red[wid] = sum;
  __syncthreads();
  sum = red[0] + red[1] + red[2] + red[3];
  const f16 den16 = (f16)sum;
  const float den = (float)den16;
#pragma unroll
  for (int i = 0; i < 2; ++i) {
    if (!act[i]) continue;
    f16x8 o;
#pragma unroll
    for (int j = 0; j < 8; ++j) {
      const int ii = i * 8 + j;
      o[j] = msk[ii] ? (f16)0.0f : (f16)((float)e16[ii] / den);
    }
    *(f16x8*)(p + (size_t)(i * 256 + t) * 8) = o;
  }
}

// ----------------------------------------------- 256^2 deep-pipeline GEMM ---
// r13 fragment-pipelined K-loop (frozen). MODE template: 0 plain,
// 1 causal skip, 2 PV K-cap.
__device__ __forceinline__ void store_out(f16* p, f16 v) { *p = v; }
__device__ __forceinline__ void store_out(float* p, f16 v) { *p = (float)v; }

template <typename OUT, int MODE>
__global__ __launch_bounds__(512, 2) void gemm256(const f16* __restrict__ A,
                                                  const f16* __restrict__ BT,
                                                  OUT* __restrict__ C,
                                                  int M, int N, int K, float alpha) {
  if (MODE == 1 && blockIdx.x > blockIdx.y) return;
  const int bm = blockIdx.y * 256, bn = blockIdx.x * 256;
  const int kend = (MODE == 2) ? (bm + 256 < K ? bm + 256 : K) : K;
  const int nt = kend >> 6;

  extern __shared__ char smem[];
  f16(*lds)[2][256][64] = (f16(*)[2][256][64])smem;  // [buf][A/B][row][col]

  const int tid = threadIdx.x;
  const int lane = tid & 63;
  const int wid = tid >> 6;          // 0..7
  const int wr = wid >> 2;           // 0..1 (M)
  const int wc = wid & 3;            // 0..3 (N)
  const f16* Ab = A + (size_t)bm * K;
  const f16* Bb = BT + (size_t)bn * K;

  const int l8 = lane >> 3;                                 // 0..7
  const int gxor8 = ((lane & 7) ^ l8) * 8;                  // staged source col
  const int lr = lane & 15;
  const int shi = lane >> 4;                                // 0..3
  const int rsw = lr & 7;                                   // read XOR key

  auto STAGE_P = [&](int p) {
    const int c = p + 6;
    const int Ts = c >> 2, hh = c & 3;
    if (Ts >= nt) return;
    const int k0 = Ts << 6;
    const int bsel = Ts & 1;
#pragma unroll
    for (int l = 0; l < 2; ++l) {
      const int rih0 = wid * 16 + l * 8;
      if (hh == 0 || hh == 3) {  // A halves (qm0 / qm1 rows)
        const int row0 = (rih0 & 63) + ((rih0 >> 6) << 7) + ((hh == 3) ? 64 : 0);
        gload_lds16(Ab + (size_t)(row0 + l8) * K + k0 + gxor8,
                    &lds[bsel][0][row0][0]);
      } else {                   // B halves (qn0 / qn1 rows)
        const int row0 = (rih0 & 31) + ((rih0 >> 5) << 6) + ((hh == 2) ? 32 : 0);
        gload_lds16(Bb + (size_t)(row0 + l8) * K + k0 + gxor8,
                    &lds[bsel][1][row0][0]);
      }
    }
  };

  f32x4 acc[8][4] = {};
  f16x8 afr0[4][2], afr1[4][2], b0r[2][2], b1r[2][2];

#pragma unroll
  for (int p = -6; p < 0; ++p) STAGE_P(p);

  for (int T = 0; T < nt; ++T) {
    const int cur = T & 1;
    // ---- ph0: seam; S0 reads; stage; tail MFMA Q11(T-1) ----
    __builtin_amdgcn_sched_barrier(0);
    if (T + 1 < nt) {
      asm volatile("s_waitcnt vmcnt(4)" ::: "memory");
    } else {
      asm volatile("s_waitcnt vmcnt(0)" ::: "memory");
    }
    __builtin_amdgcn_sched_barrier(0);
    __builtin_amdgcn_s_barrier();
    __builtin_amdgcn_sched_barrier(0);
#pragma unroll
    for (int m2 = 0; m2 < 4; ++m2)
#pragma unroll
      for (int kk = 0; kk < 2; ++kk)
        afr0[m2][kk] = *(const f16x8*)&lds[cur][0][wr * 128 + m2 * 16 + lr]
                                          [((kk * 4 + shi) ^ rsw) * 8];
#pragma unroll
    for (int n2 = 0; n2 < 2; ++n2)
#pragma unroll
      for (int kk = 0; kk < 2; ++kk)
        b0r[n2][kk] = *(const f16x8*)&lds[cur][1][wc * 64 + n2 * 16 + lr]
                                         [((kk * 4 + shi) ^ rsw) * 8];
    STAGE_P(4 * T);
    __builtin_amdgcn_sched_barrier(0);
    if (T > 0) {
#pragma unroll
      for (int m2 = 0; m2 < 4; ++m2)
#pragma unroll
        for (int n2 = 0; n2 < 2; ++n2)
#pragma unroll
          for (int kk = 0; kk < 2; ++kk)
            acc[4 + m2][2 + n2] = __builtin_amdgcn_mfma_f32_16x16x32_f16(
                afr1[m2][kk], b1r[n2][kk], acc[4 + m2][2 + n2], 0, 0, 0);
    }
    __builtin_amdgcn_sched_barrier(0);
    // ---- ph1: S1 reads; stage; MFMA Q00 ----
#pragma unroll
    for (int n2 = 0; n2 < 2; ++n2)
#pragma unroll
      for (int kk = 0; kk < 2; ++kk)
        b1r[n2][kk] = *(const f16x8*)&lds[cur][1][wc * 64 + 32 + n2 * 16 + lr]
                                         [((kk * 4 + shi) ^ rsw) * 8];
    STAGE_P(4 * T + 1);
    __builtin_amdgcn_sched_barrier(0);
#pragma unroll
    for (int m2 = 0; m2 < 4; ++m2)
#pragma unroll
      for (int n2 = 0; n2 < 2; ++n2)
#pragma unroll
        for (int kk = 0; kk < 2; ++kk)
          acc[m2][n2] = __builtin_amdgcn_mfma_f32_16x16x32_f16(
              afr0[m2][kk], b0r[n2][kk], acc[m2][n2], 0, 0, 0);
    __builtin_amdgcn_sched_barrier(0);
    // ---- ph2: safety barrier; S2 reads; stage; MFMA Q01 ----
    __builtin_amdgcn_s_barrier();
    __builtin_amdgcn_sched_barrier(0);
#pragma unroll
    for (int m2 = 0; m2 < 4; ++m2)
#pragma unroll
      for (int kk = 0; kk < 2; ++kk)
        afr1[m2][kk] = *(const f16x8*)&lds[cur][0][wr * 128 + 64 + m2 * 16 + lr]
                                          [((kk * 4 + shi) ^ rsw) * 8];
    STAGE_P(4 * T + 2);
    __builtin_amdgcn_sched_barrier(0);
#pragma unroll
    for (int m2 = 0; m2 < 4; ++m2)
#pragma unroll
      for (int n2 = 0; n2 < 2; ++n2)
#pragma unroll
        for (int kk = 0; kk < 2; ++kk)
          acc[m2][2 + n2] = __builtin_amdgcn_mfma_f32_16x16x32_f16(
              afr0[m2][kk], b1r[n2][kk], acc[m2][2 + n2], 0, 0, 0);
    __builtin_amdgcn_sched_barrier(0);
    // ---- ph3: stage; MFMA Q10 ----
    STAGE_P(4 * T + 3);
    __builtin_amdgcn_sched_barrier(0);
#pragma unroll
    for (int m2 = 0; m2 < 4; ++m2)
#pragma unroll
      for (int n2 = 0; n2 < 2; ++n2)
#pragma unroll
        for (int kk = 0; kk < 2; ++kk)
          acc[4 + m2][n2] = __builtin_amdgcn_mfma_f32_16x16x32_f16(
              afr1[m2][kk], b0r[n2][kk], acc[4 + m2][n2], 0, 0, 0);
  }
  // epilogue: final Q11
#pragma unroll
  for (int m2 = 0; m2 < 4; ++m2)
#pragma unroll
    for (int n2 = 0; n2 < 2; ++n2)
#pragma unroll
      for (int kk = 0; kk < 2; ++kk)
        acc[4 + m2][2 + n2] = __builtin_amdgcn_mfma_f32_16x16x32_f16(
            afr1[m2][kk], b1r[n2][kk], acc[4 + m2][2 + n2], 0, 0, 0);

  const int rb_l = wr * 128 + (lane >> 4) * 4;
  const int cb_l = wc * 64 + (lane & 15);

#pragma unroll
  for (int mm = 0; mm < 8; ++mm)
#pragma unroll
    for (int nn = 0; nn < 4; ++nn) {
      const int col = bn + cb_l + nn * 16;
#pragma unroll
      for (int r = 0; r < 4; ++r) {
        f16 h = (f16)acc[mm][nn][r];
        if (alpha != 1.0f) h = (f16)((float)h * alpha);
        store_out(&C[(size_t)(bm + rb_l + mm * 16 + r) * N + col], h);
      }
    }
}

// ---------------------------------------------------------------- launch ----
// d_out = FLOAT32 (64MiB): [0,32MiB) vT (f16, written by swapped v-GEMM);
// +48MiB ftab (8KB); all dead before the final f32 overwrite.
// ws: 4 slots x 32MiB: s0 xq; s1 wT->sc; s2 q->attn; s3 k->wT2.
extern "C" void kernel_launch(void* const* d_in, const int* in_sizes, int n_in,
                              void* d_out, int out_size, void* d_ws, size_t ws_size,
                              hipStream_t stream) {
  const float* x = (const float*)d_in[0];
  const float* wq = (const float*)d_in[1];
  const float* wk = (const float*)d_in[2];
  const float* wv = (const float*)d_in[3];
  const float* wo = (const float*)d_in[4];
  const float* sf = (const float*)d_in[5];
  float* out = (float*)d_out;

  const int S = S_DIM, E = E_DIM;
  const size_t U = (size_t)S * E * sizeof(f16);  // 32 MiB
  char* ws = (char*)d_ws;
  f16* xq = (f16*)(ws + 0 * U);
  f16* wT = (f16*)(ws + 1 * U);
  f16* q  = (f16*)(ws + 2 * U);
  f16* k  = (f16*)(ws + 3 * U);
  f16* vT = (f16*)d_out;                  // V^T written directly (swap)
  float* ftab = out + 12 * 1024 * 1024;   // 48MiB offset, 8KB used

  const int LDSA = 131072;
  hipFuncSetAttribute(reinterpret_cast<const void*>(&gemm256<f16, 0>),
                      hipFuncAttributeMaxDynamicSharedMemorySize, LDSA);
  hipFuncSetAttribute(reinterpret_cast<const void*>(&gemm256<f16, 1>),
                      hipFuncAttributeMaxDynamicSharedMemorySize, LDSA);
  hipFuncSetAttribute(reinterpret_cast<const void*>(&gemm256<f16, 2>),
                      hipFuncAttributeMaxDynamicSharedMemorySize, LDSA);
  hipFuncSetAttribute(reinterpret_cast<const void*>(&gemm256<float, 0>),
                      hipFuncAttributeMaxDynamicSharedMemorySize, LDSA);

  dim3 b256(256), b512(512);
  dim3 gT(E / 64, E / 64);
  dim3 gG(E / 256, S / 256);

  rmsnorm_f16<<<S, b256, 0, stream>>>(x, xq, ftab, E);

  wconv_t<<<gT, b256, 0, stream>>>(wq, sf, wT, E);
  gemm256<f16, 0><<<gG, b512, LDSA, stream>>>(xq, wT, q, S, E, E, 1.0f);
  wconv_t<<<gT, b256, 0, stream>>>(wk, sf, wT, E);
  gemm256<f16, 0><<<gG, b512, LDSA, stream>>>(xq, wT, k, S, E, E, 1.0f);
  wconv_t<<<gT, b256, 0, stream>>>(wv, sf, wT, E);
  // V^T by operand swap: vT[n][s] = sum_k wT[n,k] * xq[s,k]
  gemm256<f16, 0><<<dim3(S / 256, E / 256), b512, LDSA, stream>>>(wT, xq, vT,
                                                                  E, S, E, 1.0f);

  rope_qk<<<(S * (E / 8)) / 256, b256, 0, stream>>>(q, k, ftab, E);

  f16* sc = wT;
  gemm256<f16, 1><<<dim3(S / 256, S / 256), b512, LDSA, stream>>>(q, k, sc, S, S,
                                                                  E, 1.0f / 64.0f);
  softmax_causal<<<S, b256, 0, stream>>>(sc, S);

  f16* attn = q;
  gemm256<f16, 2><<<gG, b512, LDSA, stream>>>(sc, vT, attn, S, E, S, 1.0f);

  f16* wT2 = k;
  wconv_t<<<gT, b256, 0, stream>>>(wo, (const float*)nullptr, wT2, E);
  gemm256<float, 0><<<gG, b512, LDSA, stream>>>(attn, wT2, out, S, E, E, 1.0f);
}